// Round 5
// baseline (169.460 us; speedup 1.0000x reference)
//
#include <hip/hip_runtime.h>

// EmbeddingFreeContextAttention: B=32, L=512, D=768, fp32.
// out[b,l,k*D+d] = sent[b,l,d] * dot(sent[b,idxs[b,k],:], sent[b,l,:])
//
// R4 DIAGNOSTIC: identical kernel to R3, dispatched TWICE per launch
// (idempotent — second run rewrites the same results). dur_us delta vs R3's
// 139.7 gives the kernel's true per-dispatch time K, which rocprof's top-5
// (all harness fills) hides. K decides: optimize further vs declare roofline.

constexpr int B = 32;
constexpr int L = 512;
constexpr int D = 768;
constexpr int WAVES = 4;
constexpr int THREADS = 64 * WAVES;
constexpr int NBLK = (B * L) / WAVES;   // 4096

typedef float f4 __attribute__((ext_vector_type(4)));

__device__ __forceinline__ float dot4(f4 a, f4 b) {
    f4 p = a * b;
    return (p.x + p.y) + (p.z + p.w);
}

__global__ __launch_bounds__(THREADS)
void efca_kernel(const float* __restrict__ sent,
                 const int* __restrict__ idxs,
                 float* __restrict__ out) {
    const int wave = threadIdx.x >> 6;
    const int lane = threadIdx.x & 63;
    const int bl   = blockIdx.x * WAVES + wave;   // row id, 0..B*L-1
    const int b    = bl >> 9;                     // / L (L=512)

    const f4* __restrict__ row =
        reinterpret_cast<const f4*>(sent + (size_t)bl * D);
    const int i0 = idxs[b * 2 + 0];
    const int i1 = idxs[b * 2 + 1];
    const f4* __restrict__ e0 =
        reinterpret_cast<const f4*>(sent + (size_t)(b * L + i0) * D);
    const f4* __restrict__ e1 =
        reinterpret_cast<const f4*>(sent + (size_t)(b * L + i1) * D);

    // row: streaming (nontemporal) loads — each row is read exactly once.
    const f4 r0 = __builtin_nontemporal_load(row + lane);
    const f4 r1 = __builtin_nontemporal_load(row + lane + 64);
    const f4 r2 = __builtin_nontemporal_load(row + lane + 128);
    // entities: caching loads — reused by all 512 rows of the batch.
    const f4 a0 = e0[lane], a1 = e0[lane + 64], a2 = e0[lane + 128];
    const f4 c0 = e1[lane], c1 = e1[lane + 64], c2 = e1[lane + 128];

    float p0 = dot4(r0, a0) + dot4(r1, a1) + dot4(r2, a2);
    float p1 = dot4(r0, c0) + dot4(r1, c1) + dot4(r2, c2);

    // wave-64 butterfly: every lane ends with the full dot product.
    #pragma unroll
    for (int off = 32; off > 0; off >>= 1) {
        p0 += __shfl_xor(p0, off, 64);
        p1 += __shfl_xor(p1, off, 64);
    }

    f4* __restrict__ o = reinterpret_cast<f4*>(out + (size_t)bl * (2 * D));
    __builtin_nontemporal_store(r0 * p0, o + lane);
    __builtin_nontemporal_store(r1 * p0, o + lane + 64);
    __builtin_nontemporal_store(r2 * p0, o + lane + 128);
    __builtin_nontemporal_store(r0 * p1, o + lane + 192);
    __builtin_nontemporal_store(r1 * p1, o + lane + 256);
    __builtin_nontemporal_store(r2 * p1, o + lane + 320);
}

extern "C" void kernel_launch(void* const* d_in, const int* in_sizes, int n_in,
                              void* d_out, int out_size, void* d_ws, size_t ws_size,
                              hipStream_t stream) {
    const float* sent = (const float*)d_in[0];
    const int*   idxs = (const int*)d_in[1];
    float*       out  = (float*)d_out;

    // Dispatch twice: dur_us(R4) - dur_us(R3) == one kernel's true duration.
    efca_kernel<<<dim3(NBLK), dim3(THREADS), 0, stream>>>(sent, idxs, out);
    efca_kernel<<<dim3(NBLK), dim3(THREADS), 0, stream>>>(sent, idxs, out);
}

// Round 6
// 139.499 us; speedup vs baseline: 1.2148x; 1.2148x over previous
//
#include <hip/hip_runtime.h>

// EmbeddingFreeContextAttention: B=32, L=512, D=768, fp32.
// out[b,l,k*D+d] = sent[b,l,d] * dot(sent[b,idxs[b,k],:], sent[b,l,:])
//
// Wave-per-row: 256-thread blocks (4 waves), each wave handles one (b,l) row.
// No LDS, no __syncthreads. 64 lanes x 3 float4 = 768 floats per row.
// Entity rows via caching loads (L1/L2-hot); row loads + output stores are
// nontemporal so 144 MiB of single-use streaming doesn't evict the entities.
//
// Measured (R5 double-dispatch diagnostic): K ≈ 29.7 µs/dispatch = 5.1 TB/s
// effective on 151 MB compulsory traffic ≈ 80% of achievable ceiling.

constexpr int B = 32;
constexpr int L = 512;
constexpr int D = 768;
constexpr int WAVES = 4;
constexpr int THREADS = 64 * WAVES;
constexpr int NBLK = (B * L) / WAVES;   // 4096

typedef float f4 __attribute__((ext_vector_type(4)));

__device__ __forceinline__ float dot4(f4 a, f4 b) {
    f4 p = a * b;
    return (p.x + p.y) + (p.z + p.w);
}

__global__ __launch_bounds__(THREADS)
void efca_kernel(const float* __restrict__ sent,
                 const int* __restrict__ idxs,
                 float* __restrict__ out) {
    const int wave = threadIdx.x >> 6;
    const int lane = threadIdx.x & 63;
    const int bl   = blockIdx.x * WAVES + wave;   // row id, 0..B*L-1
    const int b    = bl >> 9;                     // / L (L=512)

    const f4* __restrict__ row =
        reinterpret_cast<const f4*>(sent + (size_t)bl * D);
    const int i0 = idxs[b * 2 + 0];
    const int i1 = idxs[b * 2 + 1];
    const f4* __restrict__ e0 =
        reinterpret_cast<const f4*>(sent + (size_t)(b * L + i0) * D);
    const f4* __restrict__ e1 =
        reinterpret_cast<const f4*>(sent + (size_t)(b * L + i1) * D);

    // row: streaming (nontemporal) loads — each row is read exactly once.
    const f4 r0 = __builtin_nontemporal_load(row + lane);
    const f4 r1 = __builtin_nontemporal_load(row + lane + 64);
    const f4 r2 = __builtin_nontemporal_load(row + lane + 128);
    // entities: caching loads — reused by all 512 rows of the batch.
    const f4 a0 = e0[lane], a1 = e0[lane + 64], a2 = e0[lane + 128];
    const f4 c0 = e1[lane], c1 = e1[lane + 64], c2 = e1[lane + 128];

    float p0 = dot4(r0, a0) + dot4(r1, a1) + dot4(r2, a2);
    float p1 = dot4(r0, c0) + dot4(r1, c1) + dot4(r2, c2);

    // wave-64 butterfly: every lane ends with the full dot product.
    #pragma unroll
    for (int off = 32; off > 0; off >>= 1) {
        p0 += __shfl_xor(p0, off, 64);
        p1 += __shfl_xor(p1, off, 64);
    }

    f4* __restrict__ o = reinterpret_cast<f4*>(out + (size_t)bl * (2 * D));
    __builtin_nontemporal_store(r0 * p0, o + lane);
    __builtin_nontemporal_store(r1 * p0, o + lane + 64);
    __builtin_nontemporal_store(r2 * p0, o + lane + 128);
    __builtin_nontemporal_store(r0 * p1, o + lane + 192);
    __builtin_nontemporal_store(r1 * p1, o + lane + 256);
    __builtin_nontemporal_store(r2 * p1, o + lane + 320);
}

extern "C" void kernel_launch(void* const* d_in, const int* in_sizes, int n_in,
                              void* d_out, int out_size, void* d_ws, size_t ws_size,
                              hipStream_t stream) {
    const float* sent = (const float*)d_in[0];
    const int*   idxs = (const int*)d_in[1];
    float*       out  = (float*)d_out;

    efca_kernel<<<dim3(NBLK), dim3(THREADS), 0, stream>>>(sent, idxs, out);
}